// Round 1
// baseline (234.326 us; speedup 1.0000x reference)
//
#include <hip/hip_runtime.h>
#include <stdint.h>

#define N_DET    4096
#define MAX_DET  100
#define NTHREADS 1024
#define SLOTS    (N_DET / NTHREADS)   // 4
#define IOU_THR  0.5f

// Explicit-rounding helpers: prevent -ffp-contract=fast from FMA-fusing and
// changing bits vs the JAX/NumPy reference.
__device__ __forceinline__ float fadd(float a, float b) { return __fadd_rn(a, b); }
__device__ __forceinline__ float fsub(float a, float b) { return __fsub_rn(a, b); }
__device__ __forceinline__ float fmul(float a, float b) { return __fmul_rn(a, b); }

struct Box { float x1, y1, x2, y2; };

// Bit-for-bit replication of the reference decode:
//   a = anchors[idx]; yc_a=(a0+a2)*0.5; xc_a=(a1+a3)*0.5; ha=a2-a0; wa=a3-a1
//   w=exp(tw)*wa; h=exp(th)*ha; yc=ty*ha+yc_a; xc=tx*wa+xc_a
//   box=[xc-w/2, yc-h/2, xc+w/2, yc+h/2]; clamp to [0, size/scale]
__device__ __forceinline__ Box decode_box(const float* __restrict__ box_b,
                                          const int*   __restrict__ idx_b,
                                          const float* __restrict__ anchors,
                                          int i, float sz0, float sz1)
{
    int ai = idx_b[i];
    float a0 = anchors[ai * 4 + 0];
    float a1 = anchors[ai * 4 + 1];
    float a2 = anchors[ai * 4 + 2];
    float a3 = anchors[ai * 4 + 3];
    float yc_a = fmul(fadd(a0, a2), 0.5f);
    float xc_a = fmul(fadd(a1, a3), 0.5f);
    float ha = fsub(a2, a0);
    float wa = fsub(a3, a1);
    float ty = box_b[i * 4 + 0];
    float tx = box_b[i * 4 + 1];
    float th = box_b[i * 4 + 2];
    float tw = box_b[i * 4 + 3];
    float we = fmul(expf(tw), wa);
    float he = fmul(expf(th), ha);
    float yc = fadd(fmul(ty, ha), yc_a);
    float xc = fadd(fmul(tx, wa), xc_a);
    Box r;
    r.x1 = fsub(xc, fmul(we, 0.5f));
    r.y1 = fsub(yc, fmul(he, 0.5f));
    r.x2 = fadd(xc, fmul(we, 0.5f));
    r.y2 = fadd(yc, fmul(he, 0.5f));
    r.x1 = fminf(fmaxf(r.x1, 0.f), sz0);
    r.y1 = fminf(fmaxf(r.y1, 0.f), sz1);
    r.x2 = fminf(fmaxf(r.x2, 0.f), sz0);
    r.y2 = fminf(fmaxf(r.y2, 0.f), sz1);
    return r;
}

__device__ __forceinline__ float sigmoidf_ref(float x)
{
    return __fdiv_rn(1.0f, __fadd_rn(1.0f, expf(-x)));
}

__global__ __launch_bounds__(NTHREADS, 1)
void effdet_nms_kernel(const float* __restrict__ cls_outputs,  // B,N,1
                       const float* __restrict__ box_outputs,  // B,N,4
                       const int*   __restrict__ indices,      // B,N
                       const int*   __restrict__ classes,      // B,N
                       const float* __restrict__ anchors,      // A,4
                       const float* __restrict__ img_scale,    // B
                       const float* __restrict__ img_size,     // B,2
                       float*       __restrict__ out)          // B,MAX_DET,6
{
    __shared__ unsigned long long keys[N_DET];  // 32 KB: (score_bits<<32)|(N-1-i)
    __shared__ float warp_red_f[16];
    __shared__ int   warp_red_i[16];
    __shared__ float sh_M;        // max(boxes)+1
    __shared__ int   sh_hpos;     // current head (sorted position), -1 when done
    __shared__ int   sh_horig;    // original index of head
    __shared__ int   sh_next;     // reduction result
    __shared__ float sh_hbox[5];  // shifted x1,y1,x2,y2,area of head
    __shared__ int   sel[MAX_DET];

    const int b = blockIdx.x;
    const int t = threadIdx.x;

    const float* cls_b    = cls_outputs + (size_t)b * N_DET;
    const float* box_b    = box_outputs + (size_t)b * N_DET * 4;
    const int*   idx_b    = indices + (size_t)b * N_DET;
    const int*   cls_id_b = classes + (size_t)b * N_DET;
    const float  scale    = img_scale[b];
    const float  sz0      = __fdiv_rn(img_size[b * 2 + 0], scale);
    const float  sz1      = __fdiv_rn(img_size[b * 2 + 1], scale);

    // ---------- Pass 1: scores -> sort keys; block max over all box coords ----------
    float lmax = 0.0f;   // coords are >= 0 after clamp
    for (int s = 0; s < SLOTS; ++s) {
        int i = t + s * NTHREADS;
        Box bx = decode_box(box_b, idx_b, anchors, i, sz0, sz1);
        lmax = fmaxf(lmax, fmaxf(fmaxf(bx.x1, bx.y1), fmaxf(bx.x2, bx.y2)));
        float sc = sigmoidf_ref(cls_b[i]);
        keys[i] = ((unsigned long long)__float_as_uint(sc) << 32) |
                  (unsigned)(N_DET - 1 - i);
    }
    for (int o = 32; o; o >>= 1) lmax = fmaxf(lmax, __shfl_xor(lmax, o, 64));
    if ((t & 63) == 0) warp_red_f[t >> 6] = lmax;
    __syncthreads();
    if (t == 0) {
        float m = warp_red_f[0];
        for (int k = 1; k < 16; ++k) m = fmaxf(m, warp_red_f[k]);
        sh_M = fadd(m, 1.0f);   // jnp.max(b) + 1.0
    }

    // ---------- Bitonic sort, descending on u64 key ----------
    for (int k = 2; k <= N_DET; k <<= 1) {
        for (int j = k >> 1; j > 0; j >>= 1) {
            __syncthreads();
            for (int v = t; v < N_DET / 2; v += NTHREADS) {
                int i   = ((v & ~(j - 1)) << 1) | (v & (j - 1));
                int ixj = i | j;
                bool desc = ((i & k) == 0);
                unsigned long long a = keys[i], c = keys[ixj];
                bool sw = desc ? (a < c) : (a > c);
                if (sw) { keys[i] = c; keys[ixj] = a; }
            }
        }
    }
    __syncthreads();

    // ---------- Pass 2: per-thread sorted boxes (class-shifted), registers ----------
    const float M = sh_M;
    float sx1[SLOTS], sy1[SLOTS], sx2[SLOTS], sy2[SLOTS], sar[SLOTS];
    int   sorig[SLOTS];
    bool  svalid[SLOTS];
    #pragma unroll
    for (int s = 0; s < SLOTS; ++s) {
        int p = t + s * NTHREADS;
        unsigned long long key = keys[p];
        int orig = N_DET - 1 - (int)(unsigned)(key & 0xFFFFFFFFull);
        Box bx = decode_box(box_b, idx_b, anchors, orig, sz0, sz1);
        float off = fmul((float)cls_id_b[orig], M);   // c.astype(f32) * (max+1)
        sx1[s] = fadd(bx.x1, off);
        sy1[s] = fadd(bx.y1, off);
        sx2[s] = fadd(bx.x2, off);
        sy2[s] = fadd(bx.y2, off);
        sar[s] = fmul(fmaxf(fsub(sx2[s], sx1[s]), 0.f),
                      fmaxf(fsub(sy2[s], sy1[s]), 0.f));
        sorig[s] = orig;
        svalid[s] = true;
    }

    // Initial head = sorted position 0 (owned by thread 0, slot 0)
    if (t == 0) {
        sh_hpos = 0; sh_horig = sorig[0];
        sh_hbox[0] = sx1[0]; sh_hbox[1] = sy1[0];
        sh_hbox[2] = sx2[0]; sh_hbox[3] = sy2[0];
        sh_hbox[4] = sar[0];
    }
    __syncthreads();

    // ---------- Greedy NMS: 100 selection steps ----------
    int it = 0;
    for (; it < MAX_DET; ++it) {
        int h = sh_hpos;
        if (h < 0) break;                         // uniform
        if (t == 0) sel[it] = sh_horig;
        float hx1 = sh_hbox[0], hy1 = sh_hbox[1];
        float hx2 = sh_hbox[2], hy2 = sh_hbox[3];
        float har = sh_hbox[4];

        int local_min = 0x7FFFFFFF;
        #pragma unroll
        for (int s = 0; s < SLOTS; ++s) {
            int p = t + s * NTHREADS;
            if (svalid[s]) {
                if (p == h) {
                    svalid[s] = false;
                } else {
                    float lt0 = fmaxf(hx1, sx1[s]);
                    float lt1 = fmaxf(hy1, sy1[s]);
                    float rb0 = fminf(hx2, sx2[s]);
                    float rb1 = fminf(hy2, sy2[s]);
                    float w0 = fmaxf(fsub(rb0, lt0), 0.f);
                    float w1 = fmaxf(fsub(rb1, lt1), 0.f);
                    float inter = fmul(w0, w1);
                    float uni = fsub(fadd(har, sar[s]), inter);
                    float iou = __fdiv_rn(inter, fmaxf(uni, 1e-8f));
                    if (iou > IOU_THR) svalid[s] = false;
                    else if (p < local_min) local_min = p;
                }
            }
        }
        // block min-reduce -> next head position
        for (int o = 32; o; o >>= 1) {
            int v = __shfl_xor(local_min, o, 64);
            if (v < local_min) local_min = v;
        }
        if ((t & 63) == 0) warp_red_i[t >> 6] = local_min;
        __syncthreads();
        if (t == 0) {
            int m = warp_red_i[0];
            for (int k = 1; k < 16; ++k) if (warp_red_i[k] < m) m = warp_red_i[k];
            sh_next = m;
        }
        __syncthreads();
        int nh = sh_next;
        if (nh == 0x7FFFFFFF) {
            if (t == 0) sh_hpos = -1;
        } else if (t == (nh & (NTHREADS - 1))) {
            int s = nh >> 10;
            float px1 = 0, py1 = 0, px2 = 0, py2 = 0, par = 0; int porig = 0;
            #pragma unroll
            for (int q = 0; q < SLOTS; ++q) {
                if (q == s) {            // keeps register-array indices constant
                    px1 = sx1[q]; py1 = sy1[q];
                    px2 = sx2[q]; py2 = sy2[q];
                    par = sar[q]; porig = sorig[q];
                }
            }
            sh_hpos = nh; sh_horig = porig;
            sh_hbox[0] = px1; sh_hbox[1] = py1;
            sh_hbox[2] = px2; sh_hbox[3] = py2;
            sh_hbox[4] = par;
        }
        __syncthreads();
    }
    // fill remaining selections with -1
    for (int k = it + t; k < MAX_DET; k += NTHREADS) sel[k] = -1;
    __syncthreads();

    // ---------- Emit output rows ----------
    if (t < MAX_DET) {
        int sidx = sel[t];
        float* o = out + (size_t)b * MAX_DET * 6 + (size_t)t * 6;
        if (sidx < 0) {
            o[0] = 0.f; o[1] = 0.f; o[2] = 0.f; o[3] = 0.f; o[4] = 0.f; o[5] = 0.f;
        } else {
            Box bx = decode_box(box_b, idx_b, anchors, sidx, sz0, sz1);
            float sc = sigmoidf_ref(cls_b[sidx]);
            int c = cls_id_b[sidx];
            o[0] = fmul(bx.x1, scale);
            o[1] = fmul(bx.y1, scale);
            o[2] = fmul(bx.x2, scale);
            o[3] = fmul(bx.y2, scale);
            o[4] = sc;
            o[5] = (float)(c + 1);
        }
    }
}

extern "C" void kernel_launch(void* const* d_in, const int* in_sizes, int n_in,
                              void* d_out, int out_size, void* d_ws, size_t ws_size,
                              hipStream_t stream)
{
    const float* cls_outputs = (const float*)d_in[0];
    const float* box_outputs = (const float*)d_in[1];
    const int*   indices     = (const int*)d_in[2];
    const int*   classes     = (const int*)d_in[3];
    const float* anchors     = (const float*)d_in[4];
    const float* img_scale   = (const float*)d_in[5];
    const float* img_size    = (const float*)d_in[6];
    float*       out         = (float*)d_out;

    const int B = in_sizes[5];   // img_scale has B elements

    effdet_nms_kernel<<<dim3(B), dim3(NTHREADS), 0, stream>>>(
        cls_outputs, box_outputs, indices, classes, anchors,
        img_scale, img_size, out);
}

// Round 2
// 79.710 us; speedup vs baseline: 2.9397x; 2.9397x over previous
//
#include <hip/hip_runtime.h>
#include <stdint.h>

#define N_DET    4096
#define MAX_DET  100
#define NTHREADS 1024
#define SLOTS    (N_DET / NTHREADS)   // 4
#define TOPC     1024                 // sorted-candidate LDS cache depth
#define IOU_THR  0.5f

// Explicit-rounding helpers: prevent -ffp-contract=fast from FMA-fusing and
// changing bits vs the JAX/NumPy reference (R1 passed with absmax 0.0 — keep
// every arithmetic path identical).
__device__ __forceinline__ float fadd(float a, float b) { return __fadd_rn(a, b); }
__device__ __forceinline__ float fsub(float a, float b) { return __fsub_rn(a, b); }
__device__ __forceinline__ float fmul(float a, float b) { return __fmul_rn(a, b); }

struct Box { float x1, y1, x2, y2; };

__device__ __forceinline__ Box decode_box(const float* __restrict__ box_b,
                                          const int*   __restrict__ idx_b,
                                          const float* __restrict__ anchors,
                                          int i, float sz0, float sz1)
{
    int ai = idx_b[i];
    float a0 = anchors[ai * 4 + 0];
    float a1 = anchors[ai * 4 + 1];
    float a2 = anchors[ai * 4 + 2];
    float a3 = anchors[ai * 4 + 3];
    float yc_a = fmul(fadd(a0, a2), 0.5f);
    float xc_a = fmul(fadd(a1, a3), 0.5f);
    float ha = fsub(a2, a0);
    float wa = fsub(a3, a1);
    float ty = box_b[i * 4 + 0];
    float tx = box_b[i * 4 + 1];
    float th = box_b[i * 4 + 2];
    float tw = box_b[i * 4 + 3];
    float we = fmul(expf(tw), wa);
    float he = fmul(expf(th), ha);
    float yc = fadd(fmul(ty, ha), yc_a);
    float xc = fadd(fmul(tx, wa), xc_a);
    Box r;
    r.x1 = fsub(xc, fmul(we, 0.5f));
    r.y1 = fsub(yc, fmul(he, 0.5f));
    r.x2 = fadd(xc, fmul(we, 0.5f));
    r.y2 = fadd(yc, fmul(he, 0.5f));
    r.x1 = fminf(fmaxf(r.x1, 0.f), sz0);
    r.y1 = fminf(fmaxf(r.y1, 0.f), sz1);
    r.x2 = fminf(fmaxf(r.x2, 0.f), sz0);
    r.y2 = fminf(fmaxf(r.y2, 0.f), sz1);
    return r;
}

__device__ __forceinline__ float sigmoidf_ref(float x)
{
    return __fdiv_rn(1.0f, __fadd_rn(1.0f, expf(-x)));
}

// Exact replication of the reference IoU row (head = row idx):
// union = area[head] + area[cand] - inter; iou = inter / max(union, 1e-8)
__device__ __forceinline__ bool iou_suppress(float hx1, float hy1, float hx2, float hy2, float har,
                                             float cx1, float cy1, float cx2, float cy2, float car)
{
    float lt0 = fmaxf(hx1, cx1);
    float lt1 = fmaxf(hy1, cy1);
    float rb0 = fminf(hx2, cx2);
    float rb1 = fminf(hy2, cy2);
    float w0 = fmaxf(fsub(rb0, lt0), 0.f);
    float w1 = fmaxf(fsub(rb1, lt1), 0.f);
    float inter = fmul(w0, w1);
    float uni = fsub(fadd(har, car), inter);
    float iou = __fdiv_rn(inter, fmaxf(uni, 1e-8f));
    return iou > IOU_THR;
}

__global__ __launch_bounds__(NTHREADS, 1)
void effdet_nms_kernel(const float* __restrict__ cls_outputs,  // B,N,1
                       const float* __restrict__ box_outputs,  // B,N,4
                       const int*   __restrict__ indices,      // B,N
                       const int*   __restrict__ classes,      // B,N
                       const float* __restrict__ anchors,      // A,4
                       const float* __restrict__ img_scale,    // B
                       const float* __restrict__ img_size,     // B,2
                       float*       __restrict__ out)          // B,MAX_DET,6
{
    __shared__ unsigned long long keys[N_DET];   // 32 KB: (score_bits<<32)|(N-1-i)
    __shared__ float cbx1[TOPC], cby1[TOPC], cbx2[TOPC], cby2[TOPC], cbar[TOPC]; // 20 KB
    __shared__ float warp_red_f[16];
    __shared__ float sh_M;                        // max(boxes)+1
    __shared__ int   sel[MAX_DET];

    const int b = blockIdx.x;
    const int t = threadIdx.x;

    const float* cls_b    = cls_outputs + (size_t)b * N_DET;
    const float* box_b    = box_outputs + (size_t)b * N_DET * 4;
    const int*   idx_b    = indices + (size_t)b * N_DET;
    const int*   cls_id_b = classes + (size_t)b * N_DET;
    const float  scale    = img_scale[b];
    const float  sz0      = __fdiv_rn(img_size[b * 2 + 0], scale);
    const float  sz1      = __fdiv_rn(img_size[b * 2 + 1], scale);

    // ---------- Pass 1: scores -> sort keys; block max over all box coords ----------
    float lmax = 0.0f;   // coords are >= 0 after clamp
    for (int s = 0; s < SLOTS; ++s) {
        int i = t + s * NTHREADS;
        Box bx = decode_box(box_b, idx_b, anchors, i, sz0, sz1);
        lmax = fmaxf(lmax, fmaxf(fmaxf(bx.x1, bx.y1), fmaxf(bx.x2, bx.y2)));
        float sc = sigmoidf_ref(cls_b[i]);
        keys[i] = ((unsigned long long)__float_as_uint(sc) << 32) |
                  (unsigned)(N_DET - 1 - i);
    }
    for (int o = 32; o; o >>= 1) lmax = fmaxf(lmax, __shfl_xor(lmax, o, 64));
    if ((t & 63) == 0) warp_red_f[t >> 6] = lmax;
    __syncthreads();
    if (t == 0) {
        float m = warp_red_f[0];
        for (int k = 1; k < 16; ++k) m = fmaxf(m, warp_red_f[k]);
        sh_M = fadd(m, 1.0f);   // jnp.max(b) + 1.0
    }

    // ---------- Bitonic sort, descending on u64 key (stable ties: lower i first) ----------
    for (int k = 2; k <= N_DET; k <<= 1) {
        for (int j = k >> 1; j > 0; j >>= 1) {
            __syncthreads();
            for (int v = t; v < N_DET / 2; v += NTHREADS) {
                int i   = ((v & ~(j - 1)) << 1) | (v & (j - 1));
                int ixj = i | j;
                bool desc = ((i & k) == 0);
                unsigned long long a = keys[i], c = keys[ixj];
                bool sw = desc ? (a < c) : (a > c);
                if (sw) { keys[i] = c; keys[ixj] = a; }
            }
        }
    }
    __syncthreads();

    // ---------- Fill LDS cache: shifted boxes + areas for top TOPC sorted ----------
    const float M = sh_M;
    {
        int p = t;   // exactly TOPC == NTHREADS
        unsigned long long key = keys[p];
        int orig = N_DET - 1 - (int)(unsigned)(key & 0xFFFFFFFFull);
        Box bb = decode_box(box_b, idx_b, anchors, orig, sz0, sz1);
        float off = fmul((float)cls_id_b[orig], M);   // c.astype(f32) * (max+1)
        float x1 = fadd(bb.x1, off), y1 = fadd(bb.y1, off);
        float x2 = fadd(bb.x2, off), y2 = fadd(bb.y2, off);
        cbx1[p] = x1; cby1[p] = y1; cbx2[p] = x2; cby2[p] = y2;
        cbar[p] = fmul(fmaxf(fsub(x2, x1), 0.f), fmaxf(fsub(y2, y1), 0.f));
    }
    __syncthreads();

    // ---------- Single-wave greedy scan (exactly equivalent to reference NMS) ----------
    if (t >= 64) return;   // no barriers beyond this point
    const int lane = t;

    for (int r = lane; r < MAX_DET; r += 64) sel[r] = -1;

    // Up to 128 selected heads live in registers: slot0 = head #lane, slot1 = head #(lane+64)
    float h0x1 = 0, h0y1 = 0, h0x2 = 0, h0y2 = 0, h0ar = 0;
    float h1x1 = 0, h1y1 = 0, h1x2 = 0, h1y2 = 0, h1ar = 0;
    bool have0 = false, have1 = false;
    int count = 0;

    for (int c = 0; c < N_DET && count < MAX_DET; ++c) {
        unsigned long long key = keys[c];
        int orig = N_DET - 1 - (int)(unsigned)(key & 0xFFFFFFFFull);
        float cx1, cy1, cx2, cy2, car;
        if (c < TOPC) {
            // broadcast LDS reads (all lanes same address)
            cx1 = cbx1[c]; cy1 = cby1[c]; cx2 = cbx2[c]; cy2 = cby2[c]; car = cbar[c];
        } else {
            // exact slow path for deep scans (correct for arbitrary data)
            Box bb = decode_box(box_b, idx_b, anchors, orig, sz0, sz1);
            float off = fmul((float)cls_id_b[orig], M);
            cx1 = fadd(bb.x1, off); cy1 = fadd(bb.y1, off);
            cx2 = fadd(bb.x2, off); cy2 = fadd(bb.y2, off);
            car = fmul(fmaxf(fsub(cx2, cx1), 0.f), fmaxf(fsub(cy2, cy1), 0.f));
        }

        bool sup = false;
        if (have0) sup = iou_suppress(h0x1, h0y1, h0x2, h0y2, h0ar, cx1, cy1, cx2, cy2, car);
        if (have1) sup = sup || iou_suppress(h1x1, h1y1, h1x2, h1y2, h1ar, cx1, cy1, cx2, cy2, car);

        if (!__any(sup ? 1 : 0)) {
            // select candidate as head #count
            if (count < 64) {
                if (lane == count) {
                    h0x1 = cx1; h0y1 = cy1; h0x2 = cx2; h0y2 = cy2; h0ar = car;
                    have0 = true;
                }
            } else {
                if (lane == count - 64) {
                    h1x1 = cx1; h1y1 = cy1; h1x2 = cx2; h1y2 = cy2; h1ar = car;
                    have1 = true;
                }
            }
            if (lane == 0) sel[count] = orig;
            ++count;
        }
    }

    // ---------- Emit output rows (wave 0, no barrier needed: same-wave LDS order) ----------
    for (int r = lane; r < MAX_DET; r += 64) {
        int sidx = sel[r];
        float* o = out + (size_t)b * MAX_DET * 6 + (size_t)r * 6;
        if (sidx < 0) {
            o[0] = 0.f; o[1] = 0.f; o[2] = 0.f; o[3] = 0.f; o[4] = 0.f; o[5] = 0.f;
        } else {
            Box bx = decode_box(box_b, idx_b, anchors, sidx, sz0, sz1);
            float sc = sigmoidf_ref(cls_b[sidx]);
            int c = cls_id_b[sidx];
            o[0] = fmul(bx.x1, scale);
            o[1] = fmul(bx.y1, scale);
            o[2] = fmul(bx.x2, scale);
            o[3] = fmul(bx.y2, scale);
            o[4] = sc;
            o[5] = (float)(c + 1);
        }
    }
}

extern "C" void kernel_launch(void* const* d_in, const int* in_sizes, int n_in,
                              void* d_out, int out_size, void* d_ws, size_t ws_size,
                              hipStream_t stream)
{
    const float* cls_outputs = (const float*)d_in[0];
    const float* box_outputs = (const float*)d_in[1];
    const int*   indices     = (const int*)d_in[2];
    const int*   classes     = (const int*)d_in[3];
    const float* anchors     = (const float*)d_in[4];
    const float* img_scale   = (const float*)d_in[5];
    const float* img_size    = (const float*)d_in[6];
    float*       out         = (float*)d_out;

    const int B = in_sizes[5];   // img_scale has B elements

    effdet_nms_kernel<<<dim3(B), dim3(NTHREADS), 0, stream>>>(
        cls_outputs, box_outputs, indices, classes, anchors,
        img_scale, img_size, out);
}

// Round 3
// 66.981 us; speedup vs baseline: 3.4984x; 1.1900x over previous
//
#include <hip/hip_runtime.h>
#include <stdint.h>

#define N_DET    4096
#define MAX_DET  100
#define NTHREADS 1024
#define TOPC     1024                 // sorted-candidate LDS cache depth
#define IOU_THR  0.5f

typedef unsigned long long u64;

// Explicit-rounding helpers: prevent -ffp-contract=fast from FMA-fusing and
// changing bits vs the JAX/NumPy reference (R1/R2 passed with absmax 0.0).
__device__ __forceinline__ float fadd(float a, float b) { return __fadd_rn(a, b); }
__device__ __forceinline__ float fsub(float a, float b) { return __fsub_rn(a, b); }
__device__ __forceinline__ float fmul(float a, float b) { return __fmul_rn(a, b); }

struct Box { float x1, y1, x2, y2; };

__device__ __forceinline__ Box decode_box(const float* __restrict__ box_b,
                                          const int*   __restrict__ idx_b,
                                          const float* __restrict__ anchors,
                                          int i, float sz0, float sz1)
{
    int ai = idx_b[i];
    float a0 = anchors[ai * 4 + 0];
    float a1 = anchors[ai * 4 + 1];
    float a2 = anchors[ai * 4 + 2];
    float a3 = anchors[ai * 4 + 3];
    float yc_a = fmul(fadd(a0, a2), 0.5f);
    float xc_a = fmul(fadd(a1, a3), 0.5f);
    float ha = fsub(a2, a0);
    float wa = fsub(a3, a1);
    float ty = box_b[i * 4 + 0];
    float tx = box_b[i * 4 + 1];
    float th = box_b[i * 4 + 2];
    float tw = box_b[i * 4 + 3];
    float we = fmul(expf(tw), wa);
    float he = fmul(expf(th), ha);
    float yc = fadd(fmul(ty, ha), yc_a);
    float xc = fadd(fmul(tx, wa), xc_a);
    Box r;
    r.x1 = fsub(xc, fmul(we, 0.5f));
    r.y1 = fsub(yc, fmul(he, 0.5f));
    r.x2 = fadd(xc, fmul(we, 0.5f));
    r.y2 = fadd(yc, fmul(he, 0.5f));
    r.x1 = fminf(fmaxf(r.x1, 0.f), sz0);
    r.y1 = fminf(fmaxf(r.y1, 0.f), sz1);
    r.x2 = fminf(fmaxf(r.x2, 0.f), sz0);
    r.y2 = fminf(fmaxf(r.y2, 0.f), sz1);
    return r;
}

__device__ __forceinline__ float sigmoidf_ref(float x)
{
    return __fdiv_rn(1.0f, __fadd_rn(1.0f, expf(-x)));
}

__device__ __forceinline__ bool iou_suppress(float hx1, float hy1, float hx2, float hy2, float har,
                                             float cx1, float cy1, float cx2, float cy2, float car)
{
    float lt0 = fmaxf(hx1, cx1);
    float lt1 = fmaxf(hy1, cy1);
    float rb0 = fminf(hx2, cx2);
    float rb1 = fminf(hy2, cy2);
    float w0 = fmaxf(fsub(rb0, lt0), 0.f);
    float w1 = fmaxf(fsub(rb1, lt1), 0.f);
    float inter = fmul(w0, w1);
    float uni = fsub(fadd(har, car), inter);
    float iou = __fdiv_rn(inter, fmaxf(uni, 1e-8f));
    return iou > IOU_THR;
}

// ---- bitonic helpers (register / shuffle phases) ----
__device__ __forceinline__ u64 shfl_xor_u64(u64 x, int mask)
{
    unsigned lo = (unsigned)x, hi = (unsigned)(x >> 32);
    lo = __shfl_xor(lo, mask, 64);
    hi = __shfl_xor(hi, mask, 64);
    return ((u64)hi << 32) | lo;
}

__device__ __forceinline__ void cex(u64& a, u64& b, bool desc)
{
    bool sw = desc ? (a < b) : (a > b);
    u64 ta = a, tb = b;
    a = sw ? tb : ta;
    b = sw ? ta : tb;
}

// One cross-lane pass: partner lane = l ^ d, element slot preserved.
// desc: sort-direction for this (k) block; lower half keeps max when desc.
__device__ __forceinline__ void shuf_pass(u64 e[4], int d, bool desc, int l)
{
    bool lower = ((l & d) == 0);
    bool keepmax = (desc == lower);
    #pragma unroll
    for (int s = 0; s < 4; ++s) {
        u64 p = shfl_xor_u64(e[s], d);
        u64 mx = (e[s] > p) ? e[s] : p;
        u64 mn = (e[s] < p) ? e[s] : p;
        e[s] = keepmax ? mx : mn;
    }
}

__global__ __launch_bounds__(NTHREADS, 1)
void effdet_nms_kernel(const float* __restrict__ cls_outputs,  // B,N,1
                       const float* __restrict__ box_outputs,  // B,N,4
                       const int*   __restrict__ indices,      // B,N
                       const int*   __restrict__ classes,      // B,N
                       const float* __restrict__ anchors,      // A,4
                       const float* __restrict__ img_scale,    // B
                       const float* __restrict__ img_size,     // B,2
                       float*       __restrict__ out)          // B,MAX_DET,6
{
    __shared__ u64   keys[N_DET];   // 32 KB: (score_bits<<32)|(N-1-i)
    __shared__ float cbx1[TOPC], cby1[TOPC], cbx2[TOPC], cby2[TOPC], cbar[TOPC]; // 20 KB
    __shared__ float warp_red_f[16];
    __shared__ int   sel[MAX_DET];

    const int b = blockIdx.x;
    const int t = threadIdx.x;
    const int l = t & 63;           // lane

    const float* cls_b    = cls_outputs + (size_t)b * N_DET;
    const float* box_b    = box_outputs + (size_t)b * N_DET * 4;
    const int*   idx_b    = indices + (size_t)b * N_DET;
    const int*   cls_id_b = classes + (size_t)b * N_DET;
    const float  scale    = img_scale[b];
    const float  sz0      = __fdiv_rn(img_size[b * 2 + 0], scale);
    const float  sz1      = __fdiv_rn(img_size[b * 2 + 1], scale);

    // ---------- Pass 1: keys straight into blocked registers; block-max of coords ----------
    // Thread t owns elements 4t..4t+3 (wave w owns contiguous 256-chunk).
    u64 e[4];
    float lmax = 0.0f;   // coords >= 0 after clamp
    #pragma unroll
    for (int s = 0; s < 4; ++s) {
        int i = 4 * t + s;
        Box bx = decode_box(box_b, idx_b, anchors, i, sz0, sz1);
        lmax = fmaxf(lmax, fmaxf(fmaxf(bx.x1, bx.y1), fmaxf(bx.x2, bx.y2)));
        float sc = sigmoidf_ref(cls_b[i]);
        e[s] = ((u64)__float_as_uint(sc) << 32) | (unsigned)(N_DET - 1 - i);
    }
    for (int o = 32; o; o >>= 1) lmax = fmaxf(lmax, __shfl_xor(lmax, o, 64));
    if (l == 0) warp_red_f[t >> 6] = lmax;   // visible after any later barrier

    // ---------- Phase A: wave-local bitonic (k = 2..256), registers + shuffles ----------
    // Global direction rule desc <=> (i & k)==0; i = 4t+s.
    cex(e[0], e[1], true);      // k=2: off&2==0 for (e0,e1)
    cex(e[2], e[3], false);     //       off&2!=0 for (e2,e3)
    for (int k = 4; k <= 128; k <<= 1) {
        bool desc = (l & (k >> 2)) == 0;
        for (int j = k >> 1; j >= 4; j >>= 1) shuf_pass(e, j >> 2, desc, l);
        cex(e[0], e[2], desc); cex(e[1], e[3], desc);   // j=2
        cex(e[0], e[1], desc); cex(e[2], e[3], desc);   // j=1
    }
    {   // k = 256: direction from wave parity (i & 256)
        bool desc = ((t >> 6) & 1) == 0;
        for (int j = 128; j >= 4; j >>= 1) shuf_pass(e, j >> 2, desc, l);
        cex(e[0], e[2], desc); cex(e[1], e[3], desc);
        cex(e[0], e[1], desc); cex(e[2], e[3], desc);
    }
    #pragma unroll
    for (int s = 0; s < 4; ++s) keys[4 * t + s] = e[s];

    // ---------- Phase B: cross-wave merges (k = 512..4096) ----------
    // j >= 256: LDS compare-exchange passes; j <= 128: register/shuffle phase.
    for (int k = 512; k <= N_DET; k <<= 1) {
        for (int j = k >> 1; j >= 256; j >>= 1) {
            __syncthreads();
            #pragma unroll
            for (int vv = 0; vv < 2; ++vv) {
                int v = t + vv * NTHREADS;
                int i   = ((v & ~(j - 1)) << 1) | (v & (j - 1));
                int ixj = i | j;
                bool desc = ((i & k) == 0);
                u64 a = keys[i], c = keys[ixj];
                bool sw = desc ? (a < c) : (a > c);
                if (sw) { keys[i] = c; keys[ixj] = a; }
            }
        }
        __syncthreads();
        u64 f[4];
        #pragma unroll
        for (int s = 0; s < 4; ++s) f[s] = keys[4 * t + s];
        bool desc = (t & (k >> 2)) == 0;
        for (int j = 128; j >= 4; j >>= 1) shuf_pass(f, j >> 2, desc, l);
        cex(f[0], f[2], desc); cex(f[1], f[3], desc);
        cex(f[0], f[1], desc); cex(f[2], f[3], desc);
        #pragma unroll
        for (int s = 0; s < 4; ++s) keys[4 * t + s] = f[s];
    }
    __syncthreads();

    // ---------- M = max(boxes) + 1 (each thread reduces the 16 wave maxima) ----------
    float mm = warp_red_f[0];
    #pragma unroll
    for (int k = 1; k < 16; ++k) mm = fmaxf(mm, warp_red_f[k]);
    const float M = fadd(mm, 1.0f);

    // ---------- Fill LDS cache: shifted boxes + areas for top TOPC sorted ----------
    {
        int p = t;   // TOPC == NTHREADS
        u64 key = keys[p];
        int orig = N_DET - 1 - (int)(unsigned)(key & 0xFFFFFFFFull);
        Box bb = decode_box(box_b, idx_b, anchors, orig, sz0, sz1);
        float off = fmul((float)cls_id_b[orig], M);   // c.astype(f32) * (max+1)
        float x1 = fadd(bb.x1, off), y1 = fadd(bb.y1, off);
        float x2 = fadd(bb.x2, off), y2 = fadd(bb.y2, off);
        cbx1[p] = x1; cby1[p] = y1; cbx2[p] = x2; cby2[p] = y2;
        cbar[p] = fmul(fmaxf(fsub(x2, x1), 0.f), fmaxf(fsub(y2, y1), 0.f));
    }
    __syncthreads();

    // ---------- Single-wave greedy scan (exactly equivalent to reference NMS) ----------
    if (t >= 64) return;   // no barriers beyond this point
    const int lane = t;

    for (int r = lane; r < MAX_DET; r += 64) sel[r] = -1;

    // Up to 128 selected heads in registers: slot0 = head #lane, slot1 = head #(lane+64)
    float h0x1 = 0, h0y1 = 0, h0x2 = 0, h0y2 = 0, h0ar = 0;
    float h1x1 = 0, h1y1 = 0, h1x2 = 0, h1y2 = 0, h1ar = 0;
    bool have0 = false, have1 = false;
    int count = 0;

    for (int c = 0; c < N_DET && count < MAX_DET; ++c) {
        u64 key = keys[c];
        int orig = N_DET - 1 - (int)(unsigned)(key & 0xFFFFFFFFull);
        float cx1, cy1, cx2, cy2, car;
        if (c < TOPC) {
            cx1 = cbx1[c]; cy1 = cby1[c]; cx2 = cbx2[c]; cy2 = cby2[c]; car = cbar[c];
        } else {
            Box bb = decode_box(box_b, idx_b, anchors, orig, sz0, sz1);
            float off = fmul((float)cls_id_b[orig], M);
            cx1 = fadd(bb.x1, off); cy1 = fadd(bb.y1, off);
            cx2 = fadd(bb.x2, off); cy2 = fadd(bb.y2, off);
            car = fmul(fmaxf(fsub(cx2, cx1), 0.f), fmaxf(fsub(cy2, cy1), 0.f));
        }

        bool sup = false;
        if (have0) sup = iou_suppress(h0x1, h0y1, h0x2, h0y2, h0ar, cx1, cy1, cx2, cy2, car);
        if (have1) sup = sup || iou_suppress(h1x1, h1y1, h1x2, h1y2, h1ar, cx1, cy1, cx2, cy2, car);

        if (!__any(sup ? 1 : 0)) {
            if (count < 64) {
                if (lane == count) {
                    h0x1 = cx1; h0y1 = cy1; h0x2 = cx2; h0y2 = cy2; h0ar = car;
                    have0 = true;
                }
            } else {
                if (lane == count - 64) {
                    h1x1 = cx1; h1y1 = cy1; h1x2 = cx2; h1y2 = cy2; h1ar = car;
                    have1 = true;
                }
            }
            if (lane == 0) sel[count] = orig;
            ++count;
        }
    }

    // ---------- Emit output rows (same wave, LDS order safe) ----------
    for (int r = lane; r < MAX_DET; r += 64) {
        int sidx = sel[r];
        float* o = out + (size_t)b * MAX_DET * 6 + (size_t)r * 6;
        if (sidx < 0) {
            o[0] = 0.f; o[1] = 0.f; o[2] = 0.f; o[3] = 0.f; o[4] = 0.f; o[5] = 0.f;
        } else {
            Box bx = decode_box(box_b, idx_b, anchors, sidx, sz0, sz1);
            float sc = sigmoidf_ref(cls_b[sidx]);
            int c = cls_id_b[sidx];
            o[0] = fmul(bx.x1, scale);
            o[1] = fmul(bx.y1, scale);
            o[2] = fmul(bx.x2, scale);
            o[3] = fmul(bx.y2, scale);
            o[4] = sc;
            o[5] = (float)(c + 1);
        }
    }
}

extern "C" void kernel_launch(void* const* d_in, const int* in_sizes, int n_in,
                              void* d_out, int out_size, void* d_ws, size_t ws_size,
                              hipStream_t stream)
{
    const float* cls_outputs = (const float*)d_in[0];
    const float* box_outputs = (const float*)d_in[1];
    const int*   indices     = (const int*)d_in[2];
    const int*   classes     = (const int*)d_in[3];
    const float* anchors     = (const float*)d_in[4];
    const float* img_scale   = (const float*)d_in[5];
    const float* img_size    = (const float*)d_in[6];
    float*       out         = (float*)d_out;

    const int B = in_sizes[5];   // img_scale has B elements

    effdet_nms_kernel<<<dim3(B), dim3(NTHREADS), 0, stream>>>(
        cls_outputs, box_outputs, indices, classes, anchors,
        img_scale, img_size, out);
}